// Round 19
// baseline (326.838 us; speedup 1.0000x reference)
//
#include <hip/hip_runtime.h>

// Problem constants
#define NV 65536     // flattened vectors (64*32*32)
#define KN 1024      // codebook size
#define DD 256       // embedding dim
#define DECAY_F 0.99f
#define OMD_F (1.0f - 0.99f)
#define EPS_F 1e-5f

typedef __attribute__((ext_vector_type(8))) short short8;
typedef __attribute__((ext_vector_type(16))) float f32x16;

// ---------------------------------------------------------------------------
// async global->LDS 16B copy. LDS dest is wave-uniform base; HW writes
// base + lane*16.
// ---------------------------------------------------------------------------
__device__ __forceinline__ void gl_lds16(const void* g, void* l) {
  __builtin_amdgcn_global_load_lds(
      (const __attribute__((address_space(1))) unsigned int*)g,
      (__attribute__((address_space(3))) unsigned int*)l, 16, 0, 0);
}

// ---------------------------------------------------------------------------
// bf16 split helpers (RTNE)
// ---------------------------------------------------------------------------
__device__ __forceinline__ void bf16_split(float v, short& hi, short& lo) {
  unsigned u = __float_as_uint(v);
  unsigned hr = (u + 0x7FFFu + ((u >> 16) & 1u)) >> 16;
  float hf = __uint_as_float(hr << 16);
  float rem = v - hf;
  unsigned u2 = __float_as_uint(rem);
  unsigned lr = (u2 + 0x7FFFu + ((u2 >> 16) & 1u)) >> 16;
  hi = (short)hr;
  lo = (short)lr;
}

__device__ __forceinline__ void split8(float4 a, float4 b, short8& h,
                                       short8& l) {
  float v[8] = {a.x, a.y, a.z, a.w, b.x, b.y, b.z, b.w};
  #pragma unroll
  for (int j = 0; j < 8; j++) {
    short hh, ll;
    bf16_split(v[j], hh, ll);
    h[j] = hh; l[j] = ll;
  }
}

// ---------------------------------------------------------------------------
// Kernel 0: prep_e (0..31) + esq (32..287) + outW pre-seed (288..799)
// + zero sseSlots/cntI (800). dw buffer is GONE: outW is pre-seeded with
// DECAY*ema_w and dw_sum atomicAdds OMD*acc into it directly.
// ---------------------------------------------------------------------------
__global__ __launch_bounds__(256) void prep_small(
    const float* __restrict__ emb, const float* __restrict__ ema_w,
    short* __restrict__ eT, float* __restrict__ eSq,
    float* __restrict__ outW, float* __restrict__ sseSlots,
    int* __restrict__ cntI) {
  const int b = blockIdx.x;
  if (b < 32) {
    // ---- prep_e: e -> MFMA tiled layout (32 tiles of 16384 shorts) ----
    const int cc = b >> 3, dc = b & 7;
    const int c = threadIdx.x;  // code within chunk, 0..255
    const float* src = emb + (cc * 256 + c) * 256 + dc * 32;
    short* tile = eT + b * 16384;
    #pragma unroll
    for (int db = 0; db < 4; db++) {
      float v[8];
      *(float4*)(v + 0) = *(const float4*)(src + db * 8);
      *(float4*)(v + 4) = *(const float4*)(src + db * 8 + 4);
      short8 h, l;
      #pragma unroll
      for (int j = 0; j < 8; j++) {
        short hh, ll;
        bf16_split(v[j], hh, ll);
        h[j] = hh; l[j] = ll;
      }
      *(short8*)(tile + ((0 * 4 + db) * 256 + c) * 8) = h;
      *(short8*)(tile + ((1 * 4 + db) * 256 + c) * 8) = l;
    }
  } else if (b < 288) {
    // ---- esq: eSq[k] = ||embedding[k]||^2. One wave per row. ----
    const int lane = threadIdx.x & 63;
    const int row = (b - 32) * 4 + (threadIdx.x >> 6);
    const float4 v = *(const float4*)(emb + row * DD + lane * 4);
    float s = v.x * v.x + v.y * v.y + v.z * v.z + v.w * v.w;
    #pragma unroll
    for (int off = 32; off > 0; off >>= 1) s += __shfl_down(s, off, 64);
    if (lane == 0) eSq[row] = s;
  } else if (b < 800) {
    // ---- outW pre-seed: outW = DECAY * ema_w (512 blocks x 512 floats) ----
    const int i = (b - 288) * 512 + threadIdx.x * 2;
    const float2 w = *(const float2*)(ema_w + i);
    float2 o;
    o.x = DECAY_F * w.x;
    o.y = DECAY_F * w.y;
    *(float2*)(outW + i) = o;
  } else {
    // ---- zero sseSlots(256) + cntI(1024) ----
    const int t = threadIdx.x;
    if (t < 256) sseSlots[t] = 0.0f;
    #pragma unroll
    for (int j = 0; j < 4; j++) cntI[t * 4 + j] = 0;
  }
}

// ---------------------------------------------------------------------------
// Kernel 1: MFMA distance + best-2 + FUSED batched rescue epilogue
// + per-block LDS histogram -> DE-CONTENDED global cntI (R19).
// This is R15's histogram component ISOLATED from its toxic fence protocol:
// no done-counter, no __threadfence — the next kernel reads cntI through
// normal stream ordering (same as idxFinal). <=120 global atomics/block,
// ~60 RMWs/address. ssf then skips its serial histogram pass (~15-20us).
// Main loop = R8 counted-vmcnt double-buffer + in-kernel fp32->bf16 conv.
// ---------------------------------------------------------------------------
__global__ __launch_bounds__(256, 2) void argmin_mfma(
    const float* __restrict__ x, const float* __restrict__ emb,
    const short* __restrict__ eT, const float* __restrict__ eSq,
    float* __restrict__ outQ, float* __restrict__ outCodes,
    int* __restrict__ idxFinal, float* __restrict__ sseSlots,
    int* __restrict__ cntI) {
  __shared__ __align__(16) char uS[67584];  // union: 2x32K stage / 66K fold
  __shared__ float eSqS[1024];
  __shared__ float sseW[4];

  float2* dbAll = (float2*)uS;

  const int tid = threadIdx.x;
  const int lane = tid & 63;
  const int wid = tid >> 6;
  const int l31 = lane & 31;
  const int lh = lane >> 5;
  const int qBase = blockIdx.x * 128 + wid * 32;

  // stage eSq once (1024 floats)
  *(float4*)(eSqS + tid * 4) = *(const float4*)(eSq + tid * 4);
  __syncthreads();  // eSqS visible to all waves BEFORE first es2 read

  float2* dbW = dbAll + wid * (64 * 33);

  float b1d = 3.4e38f, b2d = 3.4e38f;
  int b1k = 0, b2k = 1;

  const int qRow = (qBase + l31) * DD;   // fits 32-bit (16.7M max)

  const int wbase = wid * 1024;   // wave-uniform LDS sub-base (stage split)
  const int lane16 = lane * 16;   // per-lane global offset

  for (int cc = 0; cc < 4; cc++) {
    __syncthreads();  // prev-cc fold reads done / eSqS visible (cc=0)

    // prologue: stage tile (cc,0) into buf0 (8 VMEM ops outstanding)
    {
      const char* src = (const char*)(eT + (cc * 8 + 0) * 16384);
      #pragma unroll
      for (int i = 0; i < 8; i++)
        gl_lds16(src + i * 4096 + wbase + lane16, uS + i * 4096 + wbase);
    }

    f32x16 acc[8];
    #pragma unroll
    for (int ct = 0; ct < 8; ct++)
      #pragma unroll
      for (int i = 0; i < 16; i++) acc[ct][i] = 0.0f;

    float es2[8];
    #pragma unroll
    for (int ct = 0; ct < 8; ct++) es2[ct] = eSqS[cc * 256 + ct * 32 + l31];

    for (int dc = 0; dc < 8; dc++) {
      const int cur = dc & 1;
      const short* eS = (const short*)(uS + cur * 32768);

      // Raw A-data (4 float4 VMEM loads), pinned BEFORE the stage-next
      // block for deterministic vmcnt math.
      float4 ra0, rb0, ra1, rb1;
      {
        const float* xr = x + qRow + dc * 32 + lh * 8;
        ra0 = *(const float4*)(xr);
        rb0 = *(const float4*)(xr + 4);
        ra1 = *(const float4*)(xr + 16);
        rb1 = *(const float4*)(xr + 20);
      }
      __builtin_amdgcn_sched_barrier(0);

      if (dc < 7) {
        const char* src = (const char*)(eT + (cc * 8 + dc + 1) * 16384);
        char* dst = uS + (cur ^ 1) * 32768;
        #pragma unroll
        for (int i = 0; i < 8; i++)
          gl_lds16(src + i * 4096 + wbase + lane16, dst + i * 4096 + wbase);
        // outstanding: tile_dc(8 oldest) + A(4) + stage_next(8) = 20
        asm volatile("s_waitcnt vmcnt(12)" ::: "memory");
      } else {
        // outstanding: tile_7(8) + A(4) = 12
        asm volatile("s_waitcnt vmcnt(4)" ::: "memory");
      }
      __builtin_amdgcn_s_barrier();   // all waves: tile dc fully in LDS
      asm volatile("" ::: "memory");

      // convert raw fp32 -> bf16 hi/lo fragments (VALU; overlaps MFMA pipe)
      short8 ahi0, alo0, ahi1, alo1;
      split8(ra0, rb0, ahi0, alo0);
      split8(ra1, rb1, ahi1, alo1);

      // MFMA phase on buf[cur]
      #pragma unroll
      for (int ks = 0; ks < 2; ks++) {
        const short8 ahi = ks ? ahi1 : ahi0;
        const short8 alo = ks ? alo1 : alo0;
        const int db = ks * 2 + lh;
        #pragma unroll
        for (int ct = 0; ct < 8; ct++) {
          const int cL = ct * 32 + l31;
          const short8 bhi = *(const short8*)(eS + ((0 * 4 + db) * 256 + cL) * 8);
          const short8 blo = *(const short8*)(eS + ((1 * 4 + db) * 256 + cL) * 8);
          acc[ct] = __builtin_amdgcn_mfma_f32_32x32x16_bf16(ahi, bhi, acc[ct], 0, 0, 0);
          acc[ct] = __builtin_amdgcn_mfma_f32_32x32x16_bf16(ahi, blo, acc[ct], 0, 0, 0);
          acc[ct] = __builtin_amdgcn_mfma_f32_32x32x16_bf16(alo, bhi, acc[ct], 0, 0, 0);
        }
      }

      asm volatile("" ::: "memory");
      __builtin_amdgcn_s_barrier();   // all waves done reading buf[cur]
      asm volatile("" ::: "memory");
    }

    __syncthreads();  // all waves past MFMA reads; uS becomes fold buffer

    // per-(lane,reg): exact best2 over the 8 ct codes; transpose via LDS.
    #pragma unroll
    for (int r = 0; r < 16; r++) {
      const int row = (r & 3) + 8 * (r >> 2) + 4 * lh;  // query row 0..31
      float cb1 = 3.4e38f, cb2 = 3.4e38f;
      int ck1 = 0, ck2 = 0;
      #pragma unroll
      for (int ct = 0; ct < 8; ct++) {
        const float dd = es2[ct] - 2.0f * acc[ct][r];
        const int k = cc * 256 + ct * 32 + l31;
        if (dd < cb1) { cb2 = cb1; ck2 = ck1; cb1 = dd; ck1 = k; }
        else if (dd < cb2) { cb2 = dd; ck2 = k; }
      }
      dbW[(l31 * 2 + 0) * 33 + row] = make_float2(cb1, __int_as_float(ck1));
      dbW[(l31 * 2 + 1) * 33 + row] = make_float2(cb2, __int_as_float(ck2));
    }
    __syncthreads();  // transpose visible

    #pragma unroll
    for (int i = 0; i < 32; i++) {
      const float2 c = dbW[(lh * 32 + i) * 33 + l31];
      const float dd = c.x;
      const int k = __float_as_int(c.y);
      if (dd < b1d) { b2d = b1d; b2k = b1k; b1d = dd; b1k = k; }
      else if (dd < b2d) { b2d = dd; b2k = k; }
    }
  }

  // merge lane pairs (l, l+32): exact best2 of the union, k-tiebreak
  {
    const float p1d = __shfl_xor(b1d, 32, 64);
    const int p1k = __shfl_xor(b1k, 32, 64);
    const float p2d = __shfl_xor(b2d, 32, 64);
    const int p2k = __shfl_xor(b2k, 32, 64);
    if ((p1d < b1d) || (p1d == b1d && p1k < b1k)) {
      b2d = b1d; b2k = b1k; b1d = p1d; b1k = p1k;
    } else if ((p1d < b2d) || (p1d == b2d && p1k < b2k)) {
      b2d = p1d; b2k = p1k;
    }
    if ((p2d < b1d) || (p2d == b1d && p2k < b1k)) {
      b2d = b1d; b2k = b1k; b1d = p2d; b1k = p2k;
    } else if ((p2d < b2d) || (p2d == b2d && p2k < b2k)) {
      b2d = p2d; b2k = p2k;
    }
  }

  // ---- epilogue: batched rescue + per-block LDS histogram ----
  __syncthreads();  // all waves' fold reads done; uS repurposed as lhist
  int* lhist = (int*)uS;  // 4 KB
  for (int i = tid; i < 1024; i += 256) lhist[i] = 0;
  __syncthreads();

  float sseAcc = 0.0f;
  for (int qb = 0; qb < 32; qb += 4) {
    int k1[4], k2[4];
    #pragma unroll
    for (int j = 0; j < 4; j++) {
      k1[j] = __shfl(b1k, qb + j, 64);
      k2[j] = __shfl(b2k, qb + j, 64);
    }
    float4 xv[4], e1[4], e2[4];
    #pragma unroll
    for (int j = 0; j < 4; j++) {
      const int n = qBase + qb + j;
      xv[j] = *(const float4*)(x + n * DD + lane * 4);
      e1[j] = *(const float4*)(emb + k1[j] * DD + lane * 4);
      e2[j] = *(const float4*)(emb + k2[j] * DD + lane * 4);
    }
    #pragma unroll
    for (int j = 0; j < 4; j++) {
      const int n = qBase + qb + j;
      float p1 = e1[j].x * (e1[j].x - 2.0f * xv[j].x) +
                 e1[j].y * (e1[j].y - 2.0f * xv[j].y) +
                 e1[j].z * (e1[j].z - 2.0f * xv[j].z) +
                 e1[j].w * (e1[j].w - 2.0f * xv[j].w);
      float p2 = e2[j].x * (e2[j].x - 2.0f * xv[j].x) +
                 e2[j].y * (e2[j].y - 2.0f * xv[j].y) +
                 e2[j].z * (e2[j].z - 2.0f * xv[j].z) +
                 e2[j].w * (e2[j].w - 2.0f * xv[j].w);
      #pragma unroll
      for (int m = 32; m > 0; m >>= 1) {
        p1 += __shfl_xor(p1, m, 64);
        p2 += __shfl_xor(p2, m, 64);
      }
      const bool pick2 = (p2 < p1) || (p2 == p1 && k2[j] < k1[j]);
      const int ksel = pick2 ? k2[j] : k1[j];
      const float4 ev = pick2 ? e2[j] : e1[j];

      *(float4*)(outQ + n * DD + lane * 4) = ev;

      const float d0 = ev.x - xv[j].x, d1 = ev.y - xv[j].y,
                  d2 = ev.z - xv[j].z, d3 = ev.w - xv[j].w;
      float s = d0 * d0 + d1 * d1 + d2 * d2 + d3 * d3;
      #pragma unroll
      for (int m = 32; m > 0; m >>= 1) s += __shfl_down(s, m, 64);
      if (lane == 0) {
        sseAcc += s;               // register accumulate (no atomic here)
        idxFinal[n] = ksel;
        outCodes[n] = (float)ksel;
        atomicAdd(&lhist[ksel], 1);  // LDS, <=128 incs/block
      }
    }
  }
  if (lane == 0) sseW[wid] = sseAcc;
  __syncthreads();  // lhist + sseW complete

  // de-contended global histogram: one atomic per (block, nonzero code)
  for (int k = tid; k < 1024; k += 256) {
    const int c = lhist[k];
    if (c) atomicAdd(&cntI[k], c);
  }
  if (tid == 0) {
    const float t = (sseW[0] + sseW[1]) + (sseW[2] + sseW[3]);
    atomicAdd(&sseSlots[blockIdx.x & 255], t);
  }
}

// ---------------------------------------------------------------------------
// Kernel 2: FUSED scan + finalize1 + scatter. Single 1024-thread block.
// R19: histogram pass DELETED — counts come from cntI (computed de-contended
// in argmin; visible via normal kernel-boundary stream ordering).
// ---------------------------------------------------------------------------
__global__ __launch_bounds__(1024) void scan_scatter_fin(
    const int* __restrict__ idxFinal, const int* __restrict__ cntI,
    const float* __restrict__ ema_cs, const float* __restrict__ sseSlots,
    int* __restrict__ perm, float* __restrict__ norm,
    float* __restrict__ outCS, float* __restrict__ outLoss) {
  __shared__ int si[1024];
  __shared__ int cur[1024];
  __shared__ float red[1024];
  const int t = threadIdx.x;
  const int v = cntI[t];

  si[t] = v;
  __syncthreads();
  #pragma unroll
  for (int off = 1; off < 1024; off <<= 1) {
    const int add = (t >= off) ? si[t - off] : 0;
    __syncthreads();
    si[t] += add;
    __syncthreads();
  }
  cur[t] = si[t] - v;  // exclusive prefix = segment start

  // finalize1 part
  const float ncs = DECAY_F * ema_cs[t] + OMD_F * (float)v;
  outCS[t] = ncs;
  red[t] = ncs;
  __syncthreads();
  #pragma unroll
  for (int s = 512; s > 0; s >>= 1) {
    if (t < s) red[t] += red[t + s];
    __syncthreads();
  }
  const float n = red[0];
  __syncthreads();
  norm[t] = (ncs + EPS_F) / (n + (float)KN * EPS_F) * n;

  red[t] = (t < 256) ? sseSlots[t] : 0.0f;
  __syncthreads();
  #pragma unroll
  for (int s = 512; s > 0; s >>= 1) {
    if (t < s) red[t] += red[t + s];
    __syncthreads();
  }
  if (t == 0) {
    const float mse = red[0] * (1.0f / 16777216.0f);
    outLoss[0] = 0.25f * mse;  // commitment
    outLoss[1] = mse;          // codebook
  }
  __syncthreads();  // cur[] final before scatter

  // scatter: counting sort into perm, LDS cursors
  for (int i = t; i < NV; i += 1024) {
    const int k = idxFinal[i];
    const int pos = atomicAdd(&cur[k], 1);
    perm[pos] = (k << 16) | i;
  }
}

// ---------------------------------------------------------------------------
// Kernel 3: BALANCED low-atomic segmented sum -> directly into pre-seeded
// outW (seeded with DECAY*ema_w by prep; we add OMD*acc). R15-verified.
// Balanced shape is REQUIRED: per-code designs are single-CU-BW-bound under
// the heavy-tailed count distribution (R13/R17 both regressed ~+100us).
// ---------------------------------------------------------------------------
__global__ __launch_bounds__(256) void dw_sum(const float* __restrict__ x,
                                              const int* __restrict__ perm,
                                              float* __restrict__ outW) {
  __shared__ int sp[128];
  const int tid = threadIdx.x;
  if (tid < 128) sp[tid] = perm[blockIdx.x * 128 + tid];
  __syncthreads();
  const int w = tid >> 6;
  const int l = tid & 63;
  const int* wp = sp + w * 32;

  float4 acc = make_float4(0.0f, 0.0f, 0.0f, 0.0f);
  int kcur = wp[0] >> 16;

  #pragma unroll
  for (int c = 0; c < 4; c++) {
    float4 v[8];
    int kk[8];
    #pragma unroll
    for (int j = 0; j < 8; j++) {
      const int p = wp[c * 8 + j];
      kk[j] = p >> 16;
      v[j] = *(const float4*)(x + (long)(p & 0xFFFF) * DD + l * 4);
    }
    #pragma unroll
    for (int j = 0; j < 8; j++) {
      if (kk[j] != kcur) {
        float* drow = outW + kcur * DD + l * 4;
        atomicAdd(drow + 0, OMD_F * acc.x);
        atomicAdd(drow + 1, OMD_F * acc.y);
        atomicAdd(drow + 2, OMD_F * acc.z);
        atomicAdd(drow + 3, OMD_F * acc.w);
        acc = make_float4(0.0f, 0.0f, 0.0f, 0.0f);
        kcur = kk[j];
      }
      acc.x += v[j].x; acc.y += v[j].y;
      acc.z += v[j].z; acc.w += v[j].w;
    }
  }
  {
    float* drow = outW + kcur * DD + l * 4;
    atomicAdd(drow + 0, OMD_F * acc.x);
    atomicAdd(drow + 1, OMD_F * acc.y);
    atomicAdd(drow + 2, OMD_F * acc.z);
    atomicAdd(drow + 3, OMD_F * acc.w);
  }
}

// ---------------------------------------------------------------------------
// Kernel 4: outEmb = outW / norm (outW already final).
// ---------------------------------------------------------------------------
__global__ __launch_bounds__(256) void emb_div(
    const float* __restrict__ outW, const float* __restrict__ norm,
    float* __restrict__ outEmb) {
  const int i = blockIdx.x * 256 + threadIdx.x;  // 0..262143
  outEmb[i] = outW[i] / norm[i >> 8];
}

// ---------------------------------------------------------------------------
extern "C" void kernel_launch(void* const* d_in, const int* in_sizes, int n_in,
                              void* d_out, int out_size, void* d_ws, size_t ws_size,
                              hipStream_t stream) {
  const float* x = (const float*)d_in[0];        // [65536, 256]
  const float* emb = (const float*)d_in[1];      // [1024, 256]
  const float* ema_cs = (const float*)d_in[2];   // [1024]
  const float* ema_w = (const float*)d_in[3];    // [1024, 256]
  float* out = (float*)d_out;
  float* ws = (float*)d_ws;

  // --- workspace (float offsets) ---
  float* eSq = ws + 0;                   // 1024
  float* sseSlots = ws + 1024;           // 256   (zeroed by prep_small)
  int* cntI = (int*)(ws + 1280);         // 1024 ints (zeroed by prep_small)
  float* norm = ws + 2304;               // 1024
  int* idxFinal = (int*)(ws + 3328);     // 65536 ints
  int* perm = (int*)(ws + 68864);        // 65536 ints (packed (k<<16)|n)

  // --- final output layout (return-order flat, fp32) ---
  float* outQ = out;                    // 16777216  quantized_st
  float* outCodes = out + 16777216;     // 65536     codes (as float)
  float* outLoss = out + 16842752;      // 2         commitment, codebook
  float* outEmb = out + 16842754;       // 262144    new_embedding
  float* outCS = out + 17104898;        // 1024      new_cluster_size
  float* outW = out + 17105922;         // 262144    new_ema_w

  // eT scratch in the LATE-WRITTEN outEmb zone. Writers of this region:
  // emb_div (outEmb) and scan_scatter_fin (outCS[0..1] tail overlap) —
  // both strictly after all argmin eT reads (stream order). outW does NOT
  // overlap eT (eT ends at float 17104900 < 17105922), so prep's preseed
  // and argmin's eT reads are disjoint.
  short* eT = (short*)(out + 16842756);  // 524288 shorts (1 MB)

  prep_small<<<801, 256, 0, stream>>>(emb, ema_w, eT, eSq, outW, sseSlots,
                                      cntI);
  argmin_mfma<<<NV / 128, 256, 0, stream>>>(x, emb, eT, eSq, outQ, outCodes,
                                            idxFinal, sseSlots, cntI);
  scan_scatter_fin<<<1, 1024, 0, stream>>>(idxFinal, cntI, ema_cs, sseSlots,
                                           perm, norm, outCS, outLoss);
  dw_sum<<<NV / 128, 256, 0, stream>>>(x, perm, outW);
  emb_div<<<KN * DD / 256, 256, 0, stream>>>(outW, norm, outEmb);
}

// Round 20
// 316.996 us; speedup vs baseline: 1.0310x; 1.0310x over previous
//
#include <hip/hip_runtime.h>

// Problem constants
#define NV 65536     // flattened vectors (64*32*32)
#define KN 1024      // codebook size
#define DD 256       // embedding dim
#define DECAY_F 0.99f
#define OMD_F (1.0f - 0.99f)
#define EPS_F 1e-5f

typedef __attribute__((ext_vector_type(8))) short short8;
typedef __attribute__((ext_vector_type(16))) float f32x16;

// ---------------------------------------------------------------------------
// async global->LDS 16B copy. LDS dest is wave-uniform base; HW writes
// base + lane*16.
// ---------------------------------------------------------------------------
__device__ __forceinline__ void gl_lds16(const void* g, void* l) {
  __builtin_amdgcn_global_load_lds(
      (const __attribute__((address_space(1))) unsigned int*)g,
      (__attribute__((address_space(3))) unsigned int*)l, 16, 0, 0);
}

// ---------------------------------------------------------------------------
// bf16 split helpers (RTNE)
// ---------------------------------------------------------------------------
__device__ __forceinline__ void bf16_split(float v, short& hi, short& lo) {
  unsigned u = __float_as_uint(v);
  unsigned hr = (u + 0x7FFFu + ((u >> 16) & 1u)) >> 16;
  float hf = __uint_as_float(hr << 16);
  float rem = v - hf;
  unsigned u2 = __float_as_uint(rem);
  unsigned lr = (u2 + 0x7FFFu + ((u2 >> 16) & 1u)) >> 16;
  hi = (short)hr;
  lo = (short)lr;
}

__device__ __forceinline__ void split8(float4 a, float4 b, short8& h,
                                       short8& l) {
  float v[8] = {a.x, a.y, a.z, a.w, b.x, b.y, b.z, b.w};
  #pragma unroll
  for (int j = 0; j < 8; j++) {
    short hh, ll;
    bf16_split(v[j], hh, ll);
    h[j] = hh; l[j] = ll;
  }
}

// ---------------------------------------------------------------------------
// Kernel 0: prep_e (0..31) + esq (32..287) + outW pre-seed (288..799)
// + zero sseSlots (800). dw buffer is GONE: outW is pre-seeded with
// DECAY*ema_w and dw_sum atomicAdds OMD*acc into it directly (R15-verified).
// NO done-counter / fence protocol anywhere (R15's +82us argmin lesson).
// ---------------------------------------------------------------------------
__global__ __launch_bounds__(256) void prep_small(
    const float* __restrict__ emb, const float* __restrict__ ema_w,
    short* __restrict__ eT, float* __restrict__ eSq,
    float* __restrict__ outW, float* __restrict__ sseSlots) {
  const int b = blockIdx.x;
  if (b < 32) {
    // ---- prep_e: e -> MFMA tiled layout (32 tiles of 16384 shorts) ----
    const int cc = b >> 3, dc = b & 7;
    const int c = threadIdx.x;  // code within chunk, 0..255
    const float* src = emb + (cc * 256 + c) * 256 + dc * 32;
    short* tile = eT + b * 16384;
    #pragma unroll
    for (int db = 0; db < 4; db++) {
      float v[8];
      *(float4*)(v + 0) = *(const float4*)(src + db * 8);
      *(float4*)(v + 4) = *(const float4*)(src + db * 8 + 4);
      short8 h, l;
      #pragma unroll
      for (int j = 0; j < 8; j++) {
        short hh, ll;
        bf16_split(v[j], hh, ll);
        h[j] = hh; l[j] = ll;
      }
      *(short8*)(tile + ((0 * 4 + db) * 256 + c) * 8) = h;
      *(short8*)(tile + ((1 * 4 + db) * 256 + c) * 8) = l;
    }
  } else if (b < 288) {
    // ---- esq: eSq[k] = ||embedding[k]||^2. One wave per row. ----
    const int lane = threadIdx.x & 63;
    const int row = (b - 32) * 4 + (threadIdx.x >> 6);
    const float4 v = *(const float4*)(emb + row * DD + lane * 4);
    float s = v.x * v.x + v.y * v.y + v.z * v.z + v.w * v.w;
    #pragma unroll
    for (int off = 32; off > 0; off >>= 1) s += __shfl_down(s, off, 64);
    if (lane == 0) eSq[row] = s;
  } else if (b < 800) {
    // ---- outW pre-seed: outW = DECAY * ema_w (512 blocks x 512 floats) ----
    const int i = (b - 288) * 512 + threadIdx.x * 2;
    const float2 w = *(const float2*)(ema_w + i);
    float2 o;
    o.x = DECAY_F * w.x;
    o.y = DECAY_F * w.y;
    *(float2*)(outW + i) = o;
  } else {
    // ---- zero sseSlots(256) ----
    if (threadIdx.x < 256) sseSlots[threadIdx.x] = 0.0f;
  }
}

// ---------------------------------------------------------------------------
// Kernel 1: MFMA distance + best-2 + FUSED batched rescue epilogue.
// R14-VERBATIM (best measured: 157us, MfmaUtil 28%). De-contended atomics:
// no cntI (histogram lives in ssf's LDS), SSE = one atomicAdd per block.
// Main loop = R8 counted-vmcnt double-buffer + in-kernel fp32->bf16 conv.
// ---------------------------------------------------------------------------
__global__ __launch_bounds__(256, 2) void argmin_mfma(
    const float* __restrict__ x, const float* __restrict__ emb,
    const short* __restrict__ eT, const float* __restrict__ eSq,
    float* __restrict__ outQ, float* __restrict__ outCodes,
    int* __restrict__ idxFinal, float* __restrict__ sseSlots) {
  __shared__ __align__(16) char uS[67584];  // union: 2x32K stage / 66K fold
  __shared__ float eSqS[1024];
  __shared__ float sseW[4];

  float2* dbAll = (float2*)uS;

  const int tid = threadIdx.x;
  const int lane = tid & 63;
  const int wid = tid >> 6;
  const int l31 = lane & 31;
  const int lh = lane >> 5;
  const int qBase = blockIdx.x * 128 + wid * 32;

  // stage eSq once (1024 floats)
  *(float4*)(eSqS + tid * 4) = *(const float4*)(eSq + tid * 4);
  __syncthreads();  // eSqS visible to all waves BEFORE first es2 read

  float2* dbW = dbAll + wid * (64 * 33);

  float b1d = 3.4e38f, b2d = 3.4e38f;
  int b1k = 0, b2k = 1;

  const int qRow = (qBase + l31) * DD;   // fits 32-bit (16.7M max)

  const int wbase = wid * 1024;   // wave-uniform LDS sub-base (stage split)
  const int lane16 = lane * 16;   // per-lane global offset

  for (int cc = 0; cc < 4; cc++) {
    __syncthreads();  // prev-cc fold reads done / eSqS visible (cc=0)

    // prologue: stage tile (cc,0) into buf0 (8 VMEM ops outstanding)
    {
      const char* src = (const char*)(eT + (cc * 8 + 0) * 16384);
      #pragma unroll
      for (int i = 0; i < 8; i++)
        gl_lds16(src + i * 4096 + wbase + lane16, uS + i * 4096 + wbase);
    }

    f32x16 acc[8];
    #pragma unroll
    for (int ct = 0; ct < 8; ct++)
      #pragma unroll
      for (int i = 0; i < 16; i++) acc[ct][i] = 0.0f;

    float es2[8];
    #pragma unroll
    for (int ct = 0; ct < 8; ct++) es2[ct] = eSqS[cc * 256 + ct * 32 + l31];

    for (int dc = 0; dc < 8; dc++) {
      const int cur = dc & 1;
      const short* eS = (const short*)(uS + cur * 32768);

      // Raw A-data (4 float4 VMEM loads), pinned BEFORE the stage-next
      // block for deterministic vmcnt math.
      float4 ra0, rb0, ra1, rb1;
      {
        const float* xr = x + qRow + dc * 32 + lh * 8;
        ra0 = *(const float4*)(xr);
        rb0 = *(const float4*)(xr + 4);
        ra1 = *(const float4*)(xr + 16);
        rb1 = *(const float4*)(xr + 20);
      }
      __builtin_amdgcn_sched_barrier(0);

      if (dc < 7) {
        const char* src = (const char*)(eT + (cc * 8 + dc + 1) * 16384);
        char* dst = uS + (cur ^ 1) * 32768;
        #pragma unroll
        for (int i = 0; i < 8; i++)
          gl_lds16(src + i * 4096 + wbase + lane16, dst + i * 4096 + wbase);
        // outstanding: tile_dc(8 oldest) + A(4) + stage_next(8) = 20
        asm volatile("s_waitcnt vmcnt(12)" ::: "memory");
      } else {
        // outstanding: tile_7(8) + A(4) = 12
        asm volatile("s_waitcnt vmcnt(4)" ::: "memory");
      }
      __builtin_amdgcn_s_barrier();   // all waves: tile dc fully in LDS
      asm volatile("" ::: "memory");

      // convert raw fp32 -> bf16 hi/lo fragments (VALU; overlaps MFMA pipe)
      short8 ahi0, alo0, ahi1, alo1;
      split8(ra0, rb0, ahi0, alo0);
      split8(ra1, rb1, ahi1, alo1);

      // MFMA phase on buf[cur]
      #pragma unroll
      for (int ks = 0; ks < 2; ks++) {
        const short8 ahi = ks ? ahi1 : ahi0;
        const short8 alo = ks ? alo1 : alo0;
        const int db = ks * 2 + lh;
        #pragma unroll
        for (int ct = 0; ct < 8; ct++) {
          const int cL = ct * 32 + l31;
          const short8 bhi = *(const short8*)(eS + ((0 * 4 + db) * 256 + cL) * 8);
          const short8 blo = *(const short8*)(eS + ((1 * 4 + db) * 256 + cL) * 8);
          acc[ct] = __builtin_amdgcn_mfma_f32_32x32x16_bf16(ahi, bhi, acc[ct], 0, 0, 0);
          acc[ct] = __builtin_amdgcn_mfma_f32_32x32x16_bf16(ahi, blo, acc[ct], 0, 0, 0);
          acc[ct] = __builtin_amdgcn_mfma_f32_32x32x16_bf16(alo, bhi, acc[ct], 0, 0, 0);
        }
      }

      asm volatile("" ::: "memory");
      __builtin_amdgcn_s_barrier();   // all waves done reading buf[cur]
      asm volatile("" ::: "memory");
    }

    __syncthreads();  // all waves past MFMA reads; uS becomes fold buffer

    // per-(lane,reg): exact best2 over the 8 ct codes; transpose via LDS.
    #pragma unroll
    for (int r = 0; r < 16; r++) {
      const int row = (r & 3) + 8 * (r >> 2) + 4 * lh;  // query row 0..31
      float cb1 = 3.4e38f, cb2 = 3.4e38f;
      int ck1 = 0, ck2 = 0;
      #pragma unroll
      for (int ct = 0; ct < 8; ct++) {
        const float dd = es2[ct] - 2.0f * acc[ct][r];
        const int k = cc * 256 + ct * 32 + l31;
        if (dd < cb1) { cb2 = cb1; ck2 = ck1; cb1 = dd; ck1 = k; }
        else if (dd < cb2) { cb2 = dd; ck2 = k; }
      }
      dbW[(l31 * 2 + 0) * 33 + row] = make_float2(cb1, __int_as_float(ck1));
      dbW[(l31 * 2 + 1) * 33 + row] = make_float2(cb2, __int_as_float(ck2));
    }
    __syncthreads();  // transpose visible

    #pragma unroll
    for (int i = 0; i < 32; i++) {
      const float2 c = dbW[(lh * 32 + i) * 33 + l31];
      const float dd = c.x;
      const int k = __float_as_int(c.y);
      if (dd < b1d) { b2d = b1d; b2k = b1k; b1d = dd; b1k = k; }
      else if (dd < b2d) { b2d = dd; b2k = k; }
    }
  }

  // merge lane pairs (l, l+32): exact best2 of the union, k-tiebreak
  {
    const float p1d = __shfl_xor(b1d, 32, 64);
    const int p1k = __shfl_xor(b1k, 32, 64);
    const float p2d = __shfl_xor(b2d, 32, 64);
    const int p2k = __shfl_xor(b2k, 32, 64);
    if ((p1d < b1d) || (p1d == b1d && p1k < b1k)) {
      b2d = b1d; b2k = b1k; b1d = p1d; b1k = p1k;
    } else if ((p1d < b2d) || (p1d == b2d && p1k < b2k)) {
      b2d = p1d; b2k = p1k;
    }
    if ((p2d < b1d) || (p2d == b1d && p2k < b1k)) {
      b2d = b1d; b2k = b1k; b1d = p2d; b1k = p2k;
    } else if ((p2d < b2d) || (p2d == b2d && p2k < b2k)) {
      b2d = p2d; b2k = p2k;
    }
  }

  // ---- FUSED batched rescue epilogue (R14 form, atomics de-contended) ----
  float sseAcc = 0.0f;
  for (int qb = 0; qb < 32; qb += 4) {
    int k1[4], k2[4];
    #pragma unroll
    for (int j = 0; j < 4; j++) {
      k1[j] = __shfl(b1k, qb + j, 64);
      k2[j] = __shfl(b2k, qb + j, 64);
    }
    float4 xv[4], e1[4], e2[4];
    #pragma unroll
    for (int j = 0; j < 4; j++) {
      const int n = qBase + qb + j;
      xv[j] = *(const float4*)(x + n * DD + lane * 4);
      e1[j] = *(const float4*)(emb + k1[j] * DD + lane * 4);
      e2[j] = *(const float4*)(emb + k2[j] * DD + lane * 4);
    }
    #pragma unroll
    for (int j = 0; j < 4; j++) {
      const int n = qBase + qb + j;
      float p1 = e1[j].x * (e1[j].x - 2.0f * xv[j].x) +
                 e1[j].y * (e1[j].y - 2.0f * xv[j].y) +
                 e1[j].z * (e1[j].z - 2.0f * xv[j].z) +
                 e1[j].w * (e1[j].w - 2.0f * xv[j].w);
      float p2 = e2[j].x * (e2[j].x - 2.0f * xv[j].x) +
                 e2[j].y * (e2[j].y - 2.0f * xv[j].y) +
                 e2[j].z * (e2[j].z - 2.0f * xv[j].z) +
                 e2[j].w * (e2[j].w - 2.0f * xv[j].w);
      #pragma unroll
      for (int m = 32; m > 0; m >>= 1) {
        p1 += __shfl_xor(p1, m, 64);
        p2 += __shfl_xor(p2, m, 64);
      }
      const bool pick2 = (p2 < p1) || (p2 == p1 && k2[j] < k1[j]);
      const int ksel = pick2 ? k2[j] : k1[j];
      const float4 ev = pick2 ? e2[j] : e1[j];

      *(float4*)(outQ + n * DD + lane * 4) = ev;

      const float d0 = ev.x - xv[j].x, d1 = ev.y - xv[j].y,
                  d2 = ev.z - xv[j].z, d3 = ev.w - xv[j].w;
      float s = d0 * d0 + d1 * d1 + d2 * d2 + d3 * d3;
      #pragma unroll
      for (int m = 32; m > 0; m >>= 1) s += __shfl_down(s, m, 64);
      if (lane == 0) {
        sseAcc += s;               // register accumulate (no atomic here)
        idxFinal[n] = ksel;
        outCodes[n] = (float)ksel;
      }
    }
  }
  // block-level SSE combine: 4 LDS slots -> ONE global atomic per block
  if (lane == 0) sseW[wid] = sseAcc;
  __syncthreads();
  if (tid == 0) {
    const float t = (sseW[0] + sseW[1]) + (sseW[2] + sseW[3]);
    atomicAdd(&sseSlots[blockIdx.x & 255], t);
  }
}

// ---------------------------------------------------------------------------
// Kernel 2: FUSED histogram + scan + finalize1 + scatter. Single 1024-thread
// block (R14 verbatim). Counts from LDS histogram over idxFinal.
// ---------------------------------------------------------------------------
__global__ __launch_bounds__(1024) void scan_scatter_fin(
    const int* __restrict__ idxFinal, const float* __restrict__ ema_cs,
    const float* __restrict__ sseSlots, int* __restrict__ perm,
    float* __restrict__ norm, float* __restrict__ outCS,
    float* __restrict__ outLoss) {
  __shared__ int hist[1024];
  __shared__ int si[1024];
  __shared__ int cur[1024];
  __shared__ float red[1024];
  const int t = threadIdx.x;

  // LDS histogram of final indices
  hist[t] = 0;
  __syncthreads();
  for (int i = t; i < NV; i += 1024) atomicAdd(&hist[idxFinal[i]], 1);
  __syncthreads();
  const int v = hist[t];

  si[t] = v;
  __syncthreads();
  #pragma unroll
  for (int off = 1; off < 1024; off <<= 1) {
    const int add = (t >= off) ? si[t - off] : 0;
    __syncthreads();
    si[t] += add;
    __syncthreads();
  }
  cur[t] = si[t] - v;  // exclusive prefix = segment start

  // finalize1 part
  const float ncs = DECAY_F * ema_cs[t] + OMD_F * (float)v;
  outCS[t] = ncs;
  red[t] = ncs;
  __syncthreads();
  #pragma unroll
  for (int s = 512; s > 0; s >>= 1) {
    if (t < s) red[t] += red[t + s];
    __syncthreads();
  }
  const float n = red[0];
  __syncthreads();
  norm[t] = (ncs + EPS_F) / (n + (float)KN * EPS_F) * n;

  red[t] = (t < 256) ? sseSlots[t] : 0.0f;
  __syncthreads();
  #pragma unroll
  for (int s = 512; s > 0; s >>= 1) {
    if (t < s) red[t] += red[t + s];
    __syncthreads();
  }
  if (t == 0) {
    const float mse = red[0] * (1.0f / 16777216.0f);
    outLoss[0] = 0.25f * mse;  // commitment
    outLoss[1] = mse;          // codebook
  }
  __syncthreads();  // cur[] final before scatter

  // scatter: counting sort into perm, LDS cursors
  for (int i = t; i < NV; i += 1024) {
    const int k = idxFinal[i];
    const int pos = atomicAdd(&cur[k], 1);
    perm[pos] = (k << 16) | i;
  }
}

// ---------------------------------------------------------------------------
// Kernel 3: BALANCED low-atomic segmented sum -> directly into pre-seeded
// outW (seeded with DECAY*ema_w by prep; we add OMD*acc). R15-verified.
// Balanced shape is REQUIRED: per-code designs are single-CU-BW-bound under
// the heavy-tailed count distribution (R13/R17 both regressed ~+100us).
// ---------------------------------------------------------------------------
__global__ __launch_bounds__(256) void dw_sum(const float* __restrict__ x,
                                              const int* __restrict__ perm,
                                              float* __restrict__ outW) {
  __shared__ int sp[128];
  const int tid = threadIdx.x;
  if (tid < 128) sp[tid] = perm[blockIdx.x * 128 + tid];
  __syncthreads();
  const int w = tid >> 6;
  const int l = tid & 63;
  const int* wp = sp + w * 32;

  float4 acc = make_float4(0.0f, 0.0f, 0.0f, 0.0f);
  int kcur = wp[0] >> 16;

  #pragma unroll
  for (int c = 0; c < 4; c++) {
    float4 v[8];
    int kk[8];
    #pragma unroll
    for (int j = 0; j < 8; j++) {
      const int p = wp[c * 8 + j];
      kk[j] = p >> 16;
      v[j] = *(const float4*)(x + (long)(p & 0xFFFF) * DD + l * 4);
    }
    #pragma unroll
    for (int j = 0; j < 8; j++) {
      if (kk[j] != kcur) {
        float* drow = outW + kcur * DD + l * 4;
        atomicAdd(drow + 0, OMD_F * acc.x);
        atomicAdd(drow + 1, OMD_F * acc.y);
        atomicAdd(drow + 2, OMD_F * acc.z);
        atomicAdd(drow + 3, OMD_F * acc.w);
        acc = make_float4(0.0f, 0.0f, 0.0f, 0.0f);
        kcur = kk[j];
      }
      acc.x += v[j].x; acc.y += v[j].y;
      acc.z += v[j].z; acc.w += v[j].w;
    }
  }
  {
    float* drow = outW + kcur * DD + l * 4;
    atomicAdd(drow + 0, OMD_F * acc.x);
    atomicAdd(drow + 1, OMD_F * acc.y);
    atomicAdd(drow + 2, OMD_F * acc.z);
    atomicAdd(drow + 3, OMD_F * acc.w);
  }
}

// ---------------------------------------------------------------------------
// Kernel 4: outEmb = outW / norm (outW already final).
// ---------------------------------------------------------------------------
__global__ __launch_bounds__(256) void emb_div(
    const float* __restrict__ outW, const float* __restrict__ norm,
    float* __restrict__ outEmb) {
  const int i = blockIdx.x * 256 + threadIdx.x;  // 0..262143
  outEmb[i] = outW[i] / norm[i >> 8];
}

// ---------------------------------------------------------------------------
extern "C" void kernel_launch(void* const* d_in, const int* in_sizes, int n_in,
                              void* d_out, int out_size, void* d_ws, size_t ws_size,
                              hipStream_t stream) {
  const float* x = (const float*)d_in[0];        // [65536, 256]
  const float* emb = (const float*)d_in[1];      // [1024, 256]
  const float* ema_cs = (const float*)d_in[2];   // [1024]
  const float* ema_w = (const float*)d_in[3];    // [1024, 256]
  float* out = (float*)d_out;
  float* ws = (float*)d_ws;

  // --- workspace (float offsets) ---
  float* eSq = ws + 0;                   // 1024
  float* sseSlots = ws + 1024;           // 256   (zeroed by prep_small)
  float* norm = ws + 1280;               // 1024
  int* idxFinal = (int*)(ws + 2304);     // 65536 ints
  int* perm = (int*)(ws + 67840);        // 65536 ints (packed (k<<16)|n)

  // --- final output layout (return-order flat, fp32) ---
  float* outQ = out;                    // 16777216  quantized_st
  float* outCodes = out + 16777216;     // 65536     codes (as float)
  float* outLoss = out + 16842752;      // 2         commitment, codebook
  float* outEmb = out + 16842754;       // 262144    new_embedding
  float* outCS = out + 17104898;        // 1024      new_cluster_size
  float* outW = out + 17105922;         // 262144    new_ema_w

  // eT scratch in the LATE-WRITTEN outEmb zone. Writers of this region:
  // emb_div (outEmb) and scan_scatter_fin (outCS[0..1] tail overlap) —
  // both strictly after all argmin eT reads (stream order). outW does NOT
  // overlap eT (eT ends at float 17104900 < 17105922), so prep's preseed
  // and argmin's eT reads are disjoint.
  short* eT = (short*)(out + 16842756);  // 524288 shorts (1 MB)

  prep_small<<<801, 256, 0, stream>>>(emb, ema_w, eT, eSq, outW, sseSlots);
  argmin_mfma<<<NV / 128, 256, 0, stream>>>(x, emb, eT, eSq, outQ, outCodes,
                                            idxFinal, sseSlots);
  scan_scatter_fin<<<1, 1024, 0, stream>>>(idxFinal, ema_cs, sseSlots, perm,
                                           norm, outCS, outLoss);
  dw_sum<<<NV / 128, 256, 0, stream>>>(x, perm, outW);
  emb_div<<<KN * DD / 256, 256, 0, stream>>>(outW, norm, outEmb);
}